// Round 2
// baseline (275.364 us; speedup 1.0000x reference)
//
#include <hip/hip_runtime.h>
#include <hip/hip_bf16.h>

typedef unsigned short ushort_t;
typedef __attribute__((ext_vector_type(8))) __bf16 bf16x8;
typedef __attribute__((ext_vector_type(4))) float f32x4;
typedef __attribute__((ext_vector_type(2))) unsigned int u32x2;
typedef __attribute__((ext_vector_type(8))) unsigned short us8;

#define DEV __device__ __forceinline__

constexpr int BB = 2, EE = 1024, SS = 2048, HH = 16;
constexpr float L2E = 1.44269504088896f;
constexpr float SCALE_Q = 0.125f * 1.44269504088896f; // dh^-0.5 * log2(e) folded

DEV ushort_t f2bf(float x) {
  union { float f; unsigned u; } c; c.f = x;
  unsigned u = c.u;
  return (ushort_t)((u + 0x7fffu + ((u >> 16) & 1u)) >> 16); // RNE
}

DEV unsigned cvtpk(float lo, float hi) {
  unsigned r;
  asm volatile("v_cvt_pk_bf16_f32 %0, %1, %2" : "=v"(r) : "v"(lo), "v"(hi));
  return r;
}

DEV void gload16(const void* g, void* l) {
  __builtin_amdgcn_global_load_lds((const __attribute__((address_space(1))) void*)g,
                                   (__attribute__((address_space(3))) void*)l, 16, 0, 0);
}

// ---------------- prep: transpose + f32->bf16 (q,k,v -> [b][s][e]) ----------------
struct TpArgs { const float* i0; const float* i1; const float* i2;
                ushort_t* o0; ushort_t* o1; ushort_t* o2; };

__global__ __launch_bounds__(256) void k_transpose_cvt(TpArgs a) {
  int z = blockIdx.z; int p = z >> 1; int b = z & 1;
  const float* in = (p == 0) ? a.i0 : (p == 1) ? a.i1 : a.i2;
  ushort_t* out = (p == 0) ? a.o0 : (p == 1) ? a.o1 : a.o2;
  in += (long long)b * EE * SS;
  out += (long long)b * SS * EE;
  int s0 = blockIdx.x * 64, e0 = blockIdx.y * 64;
  __shared__ __align__(16) ushort_t T[64][72];
  int t = threadIdx.x;
  int sc = (t & 15) * 4, erb = t >> 4;
#pragma unroll
  for (int it = 0; it < 4; ++it) {
    int er = erb + it * 16;
    float4 v = *(const float4*)(in + (long long)(e0 + er) * SS + s0 + sc);
    T[sc + 0][er] = f2bf(v.x);
    T[sc + 1][er] = f2bf(v.y);
    T[sc + 2][er] = f2bf(v.z);
    T[sc + 3][er] = f2bf(v.w);
  }
  __syncthreads();
#pragma unroll
  for (int it = 0; it < 2; ++it) {
    int slot = t + it * 256;
    int sr = slot >> 3, ec = (slot & 7) * 8;
    us8 v = *(const us8*)&T[sr][ec];
    *(us8*)(out + (long long)(s0 + sr) * EE + e0 + ec) = v;
  }
}

// ---------------- prep: mask transpose + scale by log2(e): maskT[b][q][k] ----------------
__global__ __launch_bounds__(256) void k_mask_t(const float* __restrict__ in,
                                                float* __restrict__ out) {
  int b = blockIdx.z;
  in += (long long)b * SS * SS;
  out += (long long)b * SS * SS;
  int k0 = blockIdx.x * 64, q0 = blockIdx.y * 64;
  __shared__ float T[64][68];
  int t = threadIdx.x;
  int qc = (t & 15) * 4, krb = t >> 4;
#pragma unroll
  for (int it = 0; it < 4; ++it) {
    int kr = krb + it * 16;
    float4 v = *(const float4*)(in + (long long)(k0 + kr) * SS + q0 + qc);
    T[qc + 0][kr] = v.x * L2E;
    T[qc + 1][kr] = v.y * L2E;
    T[qc + 2][kr] = v.z * L2E;
    T[qc + 3][kr] = v.w * L2E;
  }
  __syncthreads();
#pragma unroll
  for (int it = 0; it < 4; ++it) {
    int slot = t + it * 256;
    int qr = slot >> 4, kc = (slot & 15) * 4;
    float4 v = {T[qr][kc + 0], T[qr][kc + 1], T[qr][kc + 2], T[qr][kc + 3]};
    *(float4*)(out + (long long)(q0 + qr) * SS + k0 + kc) = v;
  }
}

// ---------------- prep: W f32 -> bf16 ----------------
struct WArgs { const float* w0; const float* w1; const float* w2; const float* w3;
               ushort_t* o0; ushort_t* o1; ushort_t* o2; ushort_t* o3; };

__global__ __launch_bounds__(256) void k_cvt_w(WArgs a) {
  int y = blockIdx.y;
  const float* in = (y == 0) ? a.w0 : (y == 1) ? a.w1 : (y == 2) ? a.w2 : a.w3;
  ushort_t* out = (y == 0) ? a.o0 : (y == 1) ? a.o1 : (y == 2) ? a.o2 : a.o3;
  long long idx = ((long long)blockIdx.x * 256 + threadIdx.x) * 4;
  float4 v = *(const float4*)(in + idx);
  unsigned lo = f2bf(v.x) | ((unsigned)f2bf(v.y) << 16);
  unsigned hi = f2bf(v.z) | ((unsigned)f2bf(v.w) << 16);
  u32x2 pk = {lo, hi};
  *(u32x2*)(out + idx) = pk;
}

// ---------------- unified GEMM: D[m][n] = sum_k A[m][k]*B[n][k]; out[col*LDo+row] ----------------
DEV void stage_tile(const ushort_t* src0, ushort_t* dst0, int w, int lane) {
#pragma unroll
  for (int i = 0; i < 2; ++i) {
    int u = w * 128 + i * 64 + lane;
    int row = u >> 2, part = u & 3;
    gload16(src0 + (long long)row * 1024 + part * 8, dst0 + (w * 128 + i * 64) * 8);
  }
}

template <bool OUTF32, bool BIASROW>
__global__ __launch_bounds__(256) void k_gemm(
    const ushort_t* __restrict__ A, long long sA,
    const ushort_t* __restrict__ Bm, long long sB,
    void* __restrict__ C, long long sC,
    const float* __restrict__ bias, float scale, int LDo) {
  constexpr int K = 1024;
  __shared__ __align__(16) ushort_t As[2][4096];
  __shared__ __align__(16) ushort_t Bs[2][4096];
  int t = threadIdx.x, lane = t & 63, w = t >> 6;
  int lq = lane & 15, g = lane >> 4;
  int m0 = blockIdx.y * 128, n0 = blockIdx.x * 128;
  const ushort_t* Ab = A + (long long)blockIdx.z * sA + (long long)m0 * K;
  const ushort_t* Bb = Bm + (long long)blockIdx.z * sB + (long long)n0 * K;

  f32x4 acc[4][4];
#pragma unroll
  for (int mi = 0; mi < 4; ++mi)
#pragma unroll
    for (int ni = 0; ni < 4; ++ni) acc[mi][ni] = (f32x4){0.f, 0.f, 0.f, 0.f};

  stage_tile(Ab, As[0], w, lane);
  stage_tile(Bb, Bs[0], w, lane);
  __syncthreads();
  int wm = w >> 1, wn = w & 1;
  for (int kt = 0; kt < K / 32; ++kt) {
    int buf = kt & 1;
    if (kt + 1 < K / 32) {
      stage_tile(Ab + (kt + 1) * 32, As[buf ^ 1], w, lane);
      stage_tile(Bb + (kt + 1) * 32, Bs[buf ^ 1], w, lane);
    }
    bf16x8 aF[4], bF[4];
#pragma unroll
    for (int mi = 0; mi < 4; ++mi)
      aF[mi] = *(const bf16x8*)&As[buf][(wm * 64 + mi * 16 + lq) * 32 + g * 8];
#pragma unroll
    for (int ni = 0; ni < 4; ++ni)
      bF[ni] = *(const bf16x8*)&Bs[buf][(wn * 64 + ni * 16 + lq) * 32 + g * 8];
#pragma unroll
    for (int mi = 0; mi < 4; ++mi)
#pragma unroll
      for (int ni = 0; ni < 4; ++ni)
        acc[mi][ni] = __builtin_amdgcn_mfma_f32_16x16x32_bf16(aF[mi], bF[ni], acc[mi][ni], 0, 0, 0);
    __syncthreads();
  }
#pragma unroll
  for (int ni = 0; ni < 4; ++ni) {
    int col = n0 + wn * 64 + ni * 16 + lq;
    float bc = BIASROW ? 0.f : bias[col];
#pragma unroll
    for (int mi = 0; mi < 4; ++mi) {
      int row0 = m0 + wm * 64 + mi * 16 + 4 * g;
      f32x4 v = acc[mi][ni];
#pragma unroll
      for (int r = 0; r < 4; ++r) {
        float bb = BIASROW ? bias[row0 + r] : bc;
        v[r] = (v[r] + bb) * scale;
      }
      if (OUTF32) {
        *(f32x4*)((float*)C + (long long)blockIdx.z * sC + (long long)col * LDo + row0) = v;
      } else {
        u32x2 pk = {cvtpk(v[0], v[1]), cvtpk(v[2], v[3])};
        *(u32x2*)((ushort_t*)C + (long long)blockIdx.z * sC + (long long)col * LDo + row0) = pk;
      }
    }
  }
}

// ---------------- fused flash attention per (b, h, q-tile 128) ----------------
// K tile LDS + per-wave P LDS are XOR-swizzled: 64B rows of 4x16B slots,
// slot' = slot ^ (row>>2 & 3). K staging keeps a LINEAR global_load_lds dest and
// applies the inverse permutation to the global source (guide rule #21).
__global__ __launch_bounds__(256) void k_attn(
    const ushort_t* __restrict__ qpT, const ushort_t* __restrict__ kpT,
    const ushort_t* __restrict__ vp, const float* __restrict__ maskT,
    ushort_t* __restrict__ attnT) {
  int t = threadIdx.x, lane = t & 63, w = t >> 6;
  int lq = lane & 15, g = lane >> 4;
  int sw = lq >> 2;  // row-swizzle term: (row>>2)&3 == lq>>2 for row = kf*16+lq
  int qt = blockIdx.x, h = blockIdx.y, b = blockIdx.z;
  int q0 = qt * 128;
  const ushort_t* qT = qpT + (long long)b * SS * EE;
  const ushort_t* kT = kpT + (long long)b * SS * EE;
  const ushort_t* vB = vp + (long long)b * EE * SS + (long long)(h * 64) * SS;
  const float* mT = maskT + (long long)b * SS * SS;
  ushort_t* aT = attnT + (long long)b * SS * EE;

  __shared__ __align__(16) ushort_t Kt[2][4096];  // dbuf [ch2][k64][c32 swz]
  __shared__ __align__(16) ushort_t Pt[4][2048];  // per-wave [ch2][q32][k32 swz]

  int qglob = q0 + w * 32;

  // Q fragments hoisted to registers (B-operand layout)
  bf16x8 qF[2][2];
#pragma unroll
  for (int qf = 0; qf < 2; ++qf)
#pragma unroll
    for (int ch = 0; ch < 2; ++ch)
      qF[qf][ch] = *(const bf16x8*)(qT + (long long)(qglob + qf * 16 + lq) * EE +
                                    h * 64 + ch * 32 + g * 8);

  auto stageK = [&](int buf, int k0) {
#pragma unroll
    for (int i = 0; i < 2; ++i) {
      int u = w * 128 + i * 64 + lane;
      int ch = u >> 8, rem = u & 255, row = rem >> 2, slot = rem & 3;
      int p = slot ^ ((row >> 2) & 3);  // inverse swizzle on global source
      gload16(kT + (long long)(k0 + row) * EE + h * 64 + ch * 32 + p * 8,
              &Kt[buf][(w * 128 + i * 64) * 8]);
    }
  };

  stageK(0, 0);
  __syncthreads();

  f32x4 accO[4][2];
#pragma unroll
  for (int cf = 0; cf < 4; ++cf)
#pragma unroll
    for (int qf = 0; qf < 2; ++qf) accO[cf][qf] = (f32x4){0.f, 0.f, 0.f, 0.f};
  float mrun[2] = {-3e38f, -3e38f};
  float lrun[2] = {0.f, 0.f};

  for (int kt = 0; kt < SS / 64; ++kt) {
    int k0 = kt * 64;
    int cur = kt & 1;
    if (kt + 1 < SS / 64) stageK(cur ^ 1, k0 + 64);

    // V fragments (A-operand of PV) direct from global — L2-resident
    bf16x8 vF[4][2];
#pragma unroll
    for (int cf = 0; cf < 4; ++cf)
#pragma unroll
      for (int ch = 0; ch < 2; ++ch)
        vF[cf][ch] = *(const bf16x8*)(vB + (long long)(cf * 16 + lq) * SS + k0 + ch * 32 + 8 * g);
    // mask (pre-transposed, pre-scaled by log2e): coalesced float4 loads
    f32x4 mv[2][4];
#pragma unroll
    for (int qf = 0; qf < 2; ++qf)
#pragma unroll
      for (int kf = 0; kf < 4; ++kf)
        mv[qf][kf] = *(const f32x4*)(mT + (long long)(qglob + qf * 16 + lq) * SS +
                                     k0 + kf * 16 + 4 * g);

    // QK^T (swapped: A=K rows, B=Q) -> accS[k][q], log2 domain
    f32x4 accS[4][2];
#pragma unroll
    for (int kf = 0; kf < 4; ++kf)
#pragma unroll
      for (int qf = 0; qf < 2; ++qf) accS[kf][qf] = (f32x4){0.f, 0.f, 0.f, 0.f};
#pragma unroll
    for (int ch = 0; ch < 2; ++ch) {
      bf16x8 aK[4];
#pragma unroll
      for (int kf = 0; kf < 4; ++kf)
        aK[kf] = *(const bf16x8*)&Kt[cur][ch * 2048 + (kf * 16 + lq) * 32 + (g ^ sw) * 8];
#pragma unroll
      for (int kf = 0; kf < 4; ++kf)
#pragma unroll
        for (int qf = 0; qf < 2; ++qf)
          accS[kf][qf] = __builtin_amdgcn_mfma_f32_16x16x32_bf16(aK[kf], qF[qf][ch], accS[kf][qf], 0, 0, 0);
    }

    // online softmax per qf (defer-max THR=8 in log2 domain)
#pragma unroll
    for (int qf = 0; qf < 2; ++qf) {
      float sv[4][4];
      float tm = -3e38f;
#pragma unroll
      for (int kf = 0; kf < 4; ++kf)
#pragma unroll
        for (int r = 0; r < 4; ++r) {
          sv[kf][r] = accS[kf][qf][r] + mv[qf][kf][r];
          tm = fmaxf(tm, sv[kf][r]);
        }
      tm = fmaxf(tm, __shfl_xor(tm, 16));
      tm = fmaxf(tm, __shfl_xor(tm, 32));
      if (__any(tm > mrun[qf] + 8.0f)) {
        float mnew = fmaxf(mrun[qf], tm);
        float corr = __builtin_amdgcn_exp2f(mrun[qf] - mnew);
        lrun[qf] *= corr;
#pragma unroll
        for (int cf = 0; cf < 4; ++cf) accO[cf][qf] = accO[cf][qf] * corr;
        mrun[qf] = mnew;
      }
      float m = mrun[qf];
      float ps = 0.f;
      unsigned pk0[4], pk1[4];
#pragma unroll
      for (int kf = 0; kf < 4; ++kf) {
        float p0 = __builtin_amdgcn_exp2f(sv[kf][0] - m);
        float p1 = __builtin_amdgcn_exp2f(sv[kf][1] - m);
        float p2 = __builtin_amdgcn_exp2f(sv[kf][2] - m);
        float p3 = __builtin_amdgcn_exp2f(sv[kf][3] - m);
        ps += (p0 + p1) + (p2 + p3);
        pk0[kf] = cvtpk(p0, p1);
        pk1[kf] = cvtpk(p2, p3);
      }
      ps += __shfl_xor(ps, 16);
      ps += __shfl_xor(ps, 32);
      lrun[qf] += ps;
      int row = qf * 16 + lq;
#pragma unroll
      for (int kf = 0; kf < 4; ++kf) {
        int slot = ((kf & 1) * 2 + (g >> 1)) ^ sw;
        u32x2 pkv = {pk0[kf], pk1[kf]};
        *(u32x2*)&Pt[w][(kf >> 1) * 1024 + row * 32 + slot * 8 + (g & 1) * 4] = pkv;
      }
    }

    // PV: accO[c][q] += V[c][k] * P[k][q]
#pragma unroll
    for (int ch = 0; ch < 2; ++ch) {
      bf16x8 bP[2];
#pragma unroll
      for (int qf = 0; qf < 2; ++qf)
        bP[qf] = *(const bf16x8*)&Pt[w][ch * 1024 + (qf * 16 + lq) * 32 + (g ^ sw) * 8];
#pragma unroll
      for (int cf = 0; cf < 4; ++cf)
#pragma unroll
        for (int qf = 0; qf < 2; ++qf)
          accO[cf][qf] = __builtin_amdgcn_mfma_f32_16x16x32_bf16(vF[cf][ch], bP[qf], accO[cf][qf], 0, 0, 0);
    }
    __syncthreads();
  }

  // epilogue: normalize, write attnT[s][c] bf16
#pragma unroll
  for (int qf = 0; qf < 2; ++qf) {
    float inv = 1.f / lrun[qf];
    int s = qglob + qf * 16 + lq;
#pragma unroll
    for (int cf = 0; cf < 4; ++cf) {
      int c0 = h * 64 + cf * 16 + 4 * g;
      f32x4 v = accO[cf][qf];
      u32x2 pk = {cvtpk(v[0] * inv, v[1] * inv), cvtpk(v[2] * inv, v[3] * inv)};
      *(u32x2*)(aT + (long long)s * EE + c0) = pk;
    }
  }
}

extern "C" void kernel_launch(void* const* d_in, const int* in_sizes, int n_in,
                              void* d_out, int out_size, void* d_ws, size_t ws_size,
                              hipStream_t stream) {
  const float* q = (const float*)d_in[0];
  const float* k = (const float*)d_in[1];
  const float* v = (const float*)d_in[2];
  const float* mask = (const float*)d_in[3];
  const float* Wq = (const float*)d_in[4];
  const float* bq = (const float*)d_in[5];
  const float* Wk = (const float*)d_in[6];
  const float* bk = (const float*)d_in[7];
  const float* Wv = (const float*)d_in[8];
  const float* bv = (const float*)d_in[9];
  const float* Wo = (const float*)d_in[10];
  const float* bo = (const float*)d_in[11];
  float* out = (float*)d_out;

  char* ws = (char*)d_ws;
  const long long MB = 1024LL * 1024LL;
  // maskT occupies [0,34MB) and is written AFTER the projection GEMMs, so the
  // x/W staging buffers below (all dead by then) can live inside that range.
  float*    mskT = (float*)(ws + 0 * MB);     // [b][q][k] f32 * L2E, 33.6MB
  ushort_t* xqT = (ushort_t*)(ws + 0 * MB);   // [b][s][e] bf16, 8MB (dead after proj)
  ushort_t* xkT = (ushort_t*)(ws + 8 * MB);
  ushort_t* xvT = (ushort_t*)(ws + 16 * MB);
  ushort_t* wqB = (ushort_t*)(ws + 24 * MB);  // 2MB each (dead after proj)
  ushort_t* wkB = (ushort_t*)(ws + 26 * MB);
  ushort_t* wvB = (ushort_t*)(ws + 28 * MB);
  ushort_t* qpT = (ushort_t*)(ws + 34 * MB);  // [b][s][c] scaled, 8MB
  ushort_t* kpT = (ushort_t*)(ws + 42 * MB);  // [b][s][c]
  ushort_t* vpN = (ushort_t*)(ws + 50 * MB);  // [b][c][s]
  ushort_t* anT = (ushort_t*)(ws + 58 * MB);  // [b][s][c]
  ushort_t* woB = (ushort_t*)(ws + 66 * MB);  // 2MB, live till final GEMM

  TpArgs tp{q, k, v, xqT, xkT, xvT};
  hipLaunchKernelGGL(k_transpose_cvt, dim3(SS / 64, EE / 64, 6), dim3(256), 0, stream, tp);
  WArgs wa{Wq, Wk, Wv, Wo, wqB, wkB, wvB, woB};
  hipLaunchKernelGGL(k_cvt_w, dim3(1024, 4, 1), dim3(256), 0, stream, wa);

  long long s2 = (long long)SS * EE;
  // qp: D[m=c][n=s] -> qpT[s][c], bias on rows (c), fold dh^-0.5*log2e
  hipLaunchKernelGGL((k_gemm<false, true>), dim3(SS / 128, EE / 128, BB), dim3(256), 0, stream,
                     wqB, 0LL, xqT, s2, (void*)qpT, s2, bq, SCALE_Q, EE);
  // kp: -> kpT[s][c]
  hipLaunchKernelGGL((k_gemm<false, true>), dim3(SS / 128, EE / 128, BB), dim3(256), 0, stream,
                     wkB, 0LL, xkT, s2, (void*)kpT, s2, bk, 1.0f, EE);
  // vp: D[m=s][n=c] -> vp[c][s], bias on cols (c)
  hipLaunchKernelGGL((k_gemm<false, false>), dim3(EE / 128, SS / 128, BB), dim3(256), 0, stream,
                     xvT, s2, wvB, 0LL, (void*)vpN, s2, bv, 1.0f, SS);
  // mask transpose (after proj GEMMs: overwrites x/W staging region)
  hipLaunchKernelGGL(k_mask_t, dim3(SS / 64, SS / 64, BB), dim3(256), 0, stream,
                     mask, mskT);
  // attention
  hipLaunchKernelGGL(k_attn, dim3(SS / 128, HH, BB), dim3(256), 0, stream,
                     qpT, kpT, vpN, mskT, anT);
  // out: D[m=s][n=o] -> out[o][s] f32, bias on cols (o)
  hipLaunchKernelGGL((k_gemm<true, false>), dim3(EE / 128, SS / 128, BB), dim3(256), 0, stream,
                     anT, s2, woB, 0LL, (void*)out, s2, bo, 1.0f, SS);
}

// Round 3
// 226.967 us; speedup vs baseline: 1.2132x; 1.2132x over previous
//
#include <hip/hip_runtime.h>
#include <hip/hip_bf16.h>

typedef unsigned short ushort_t;
typedef __attribute__((ext_vector_type(8))) __bf16 bf16x8;
typedef __attribute__((ext_vector_type(4))) float f32x4;
typedef __attribute__((ext_vector_type(2))) unsigned int u32x2;
typedef __attribute__((ext_vector_type(8))) unsigned short us8;

#define DEV __device__ __forceinline__

constexpr int BB = 2, EE = 1024, SS = 2048, HH = 16;
constexpr float L2E = 1.44269504088896f;
constexpr float SCALE_Q = 0.125f * 1.44269504088896f; // dh^-0.5 * log2(e) folded

DEV ushort_t f2bf(float x) {
  union { float f; unsigned u; } c; c.f = x;
  unsigned u = c.u;
  return (ushort_t)((u + 0x7fffu + ((u >> 16) & 1u)) >> 16); // RNE
}

DEV unsigned cvtpk(float lo, float hi) {
  unsigned r;
  asm volatile("v_cvt_pk_bf16_f32 %0, %1, %2" : "=v"(r) : "v"(lo), "v"(hi));
  return r;
}

DEV void gload16(const void* g, void* l) {
  __builtin_amdgcn_global_load_lds((const __attribute__((address_space(1))) void*)g,
                                   (__attribute__((address_space(3))) void*)l, 16, 0, 0);
}

// ---------------- prep: transpose + f32->bf16 (q,k,v -> [b][s][e]) ----------------
struct TpArgs { const float* i0; const float* i1; const float* i2;
                ushort_t* o0; ushort_t* o1; ushort_t* o2; };

__global__ __launch_bounds__(256) void k_transpose_cvt(TpArgs a) {
  int z = blockIdx.z; int p = z >> 1; int b = z & 1;
  const float* in = (p == 0) ? a.i0 : (p == 1) ? a.i1 : a.i2;
  ushort_t* out = (p == 0) ? a.o0 : (p == 1) ? a.o1 : a.o2;
  in += (long long)b * EE * SS;
  out += (long long)b * SS * EE;
  int s0 = blockIdx.x * 64, e0 = blockIdx.y * 64;
  __shared__ __align__(16) ushort_t T[64][72];
  int t = threadIdx.x;
  int sc = (t & 15) * 4, erb = t >> 4;
#pragma unroll
  for (int it = 0; it < 4; ++it) {
    int er = erb + it * 16;
    float4 v = *(const float4*)(in + (long long)(e0 + er) * SS + s0 + sc);
    T[sc + 0][er] = f2bf(v.x);
    T[sc + 1][er] = f2bf(v.y);
    T[sc + 2][er] = f2bf(v.z);
    T[sc + 3][er] = f2bf(v.w);
  }
  __syncthreads();
#pragma unroll
  for (int it = 0; it < 2; ++it) {
    int slot = t + it * 256;
    int sr = slot >> 3, ec = (slot & 7) * 8;
    us8 v = *(const us8*)&T[sr][ec];
    *(us8*)(out + (long long)(s0 + sr) * EE + e0 + ec) = v;
  }
}

// ---------------- prep: W f32 -> bf16 ----------------
struct WArgs { const float* w0; const float* w1; const float* w2; const float* w3;
               ushort_t* o0; ushort_t* o1; ushort_t* o2; ushort_t* o3; };

__global__ __launch_bounds__(256) void k_cvt_w(WArgs a) {
  int y = blockIdx.y;
  const float* in = (y == 0) ? a.w0 : (y == 1) ? a.w1 : (y == 2) ? a.w2 : a.w3;
  ushort_t* out = (y == 0) ? a.o0 : (y == 1) ? a.o1 : (y == 2) ? a.o2 : a.o3;
  long long idx = ((long long)blockIdx.x * 256 + threadIdx.x) * 4;
  float4 v = *(const float4*)(in + idx);
  unsigned lo = f2bf(v.x) | ((unsigned)f2bf(v.y) << 16);
  unsigned hi = f2bf(v.z) | ((unsigned)f2bf(v.w) << 16);
  u32x2 pk = {lo, hi};
  *(u32x2*)(out + idx) = pk;
}

// ---------------- GEMM core helpers ----------------
DEV void stage_tile(const ushort_t* src0, ushort_t* dst0, int w, int lane) {
#pragma unroll
  for (int i = 0; i < 2; ++i) {
    int u = w * 128 + i * 64 + lane;
    int row = u >> 2, part = u & 3;
    gload16(src0 + (long long)row * 1024 + part * 8, dst0 + (w * 128 + i * 64) * 8);
  }
}

// ---------------- merged projection GEMMs: z = pair*2+b, pair in {q,k,v} ----------------
__global__ __launch_bounds__(256) void k_proj(
    const ushort_t* __restrict__ xq, const ushort_t* __restrict__ xk,
    const ushort_t* __restrict__ xv, const ushort_t* __restrict__ wq,
    const ushort_t* __restrict__ wk, const ushort_t* __restrict__ wv,
    const float* __restrict__ bqp, const float* __restrict__ bkp,
    const float* __restrict__ bvp,
    ushort_t* __restrict__ qpT, ushort_t* __restrict__ kpT,
    ushort_t* __restrict__ vpN) {
  constexpr int K = 1024;
  __shared__ __align__(16) ushort_t As[2][4096];
  __shared__ __align__(16) ushort_t Bs[2][4096];
  int t = threadIdx.x, lane = t & 63, w = t >> 6;
  int lq = lane & 15, g = lane >> 4;
  int z = blockIdx.z, pair = z >> 1, b = z & 1;
  long long s2 = (long long)SS * EE;
  int m0, n0, LDo; bool browq; float scale; const float* bias;
  const ushort_t *Ab, *Bb; ushort_t* Co;
  if (pair < 2) {
    // q/k: D[m=c][n=s] -> out[s][c], bias on rows (c)
    m0 = blockIdx.y * 128; n0 = blockIdx.x * 128;
    Ab = (pair == 0 ? wq : wk) + (long long)m0 * K;
    Bb = (pair == 0 ? xq : xk) + b * s2 + (long long)n0 * K;
    Co = (pair == 0 ? qpT : kpT) + b * s2;
    bias = (pair == 0 ? bqp : bkp);
    scale = (pair == 0 ? SCALE_Q : 1.0f);
    LDo = EE; browq = true;
  } else {
    // v: D[m=s][n=c] -> out[c][s], bias on cols (c)
    m0 = blockIdx.x * 128; n0 = blockIdx.y * 128;
    Ab = xv + b * s2 + (long long)m0 * K;
    Bb = wv + (long long)n0 * K;
    Co = vpN + b * s2;
    bias = bvp; scale = 1.0f; LDo = SS; browq = false;
  }

  f32x4 acc[4][4];
#pragma unroll
  for (int mi = 0; mi < 4; ++mi)
#pragma unroll
    for (int ni = 0; ni < 4; ++ni) acc[mi][ni] = (f32x4){0.f, 0.f, 0.f, 0.f};

  stage_tile(Ab, As[0], w, lane);
  stage_tile(Bb, Bs[0], w, lane);
  __syncthreads();
  int wm = w >> 1, wn = w & 1;
  for (int kt = 0; kt < K / 32; ++kt) {
    int buf = kt & 1;
    if (kt + 1 < K / 32) {
      stage_tile(Ab + (kt + 1) * 32, As[buf ^ 1], w, lane);
      stage_tile(Bb + (kt + 1) * 32, Bs[buf ^ 1], w, lane);
    }
    bf16x8 aF[4], bF[4];
#pragma unroll
    for (int mi = 0; mi < 4; ++mi)
      aF[mi] = *(const bf16x8*)&As[buf][(wm * 64 + mi * 16 + lq) * 32 + g * 8];
#pragma unroll
    for (int ni = 0; ni < 4; ++ni)
      bF[ni] = *(const bf16x8*)&Bs[buf][(wn * 64 + ni * 16 + lq) * 32 + g * 8];
#pragma unroll
    for (int mi = 0; mi < 4; ++mi)
#pragma unroll
      for (int ni = 0; ni < 4; ++ni)
        acc[mi][ni] = __builtin_amdgcn_mfma_f32_16x16x32_bf16(aF[mi], bF[ni], acc[mi][ni], 0, 0, 0);
    __syncthreads();
  }
#pragma unroll
  for (int ni = 0; ni < 4; ++ni) {
    int col = n0 + wn * 64 + ni * 16 + lq;
    float bc = browq ? 0.f : bias[col];
#pragma unroll
    for (int mi = 0; mi < 4; ++mi) {
      int row0 = m0 + wm * 64 + mi * 16 + 4 * g;
      f32x4 v = acc[mi][ni];
#pragma unroll
      for (int r = 0; r < 4; ++r) {
        float bb = browq ? bias[row0 + r] : bc;
        v[r] = (v[r] + bb) * scale;
      }
      u32x2 pk = {cvtpk(v[0], v[1]), cvtpk(v[2], v[3])};
      *(u32x2*)(Co + (long long)col * LDo + row0) = pk;
    }
  }
}

// ---------------- final GEMM: D[m][n] = sum_k A[m][k]*B[n][k]; out f32 [col][row] ----------------
__global__ __launch_bounds__(256) void k_gemm_out(
    const ushort_t* __restrict__ A, long long sA,
    const ushort_t* __restrict__ Bm,
    float* __restrict__ C, long long sC,
    const float* __restrict__ bias, int LDo) {
  constexpr int K = 1024;
  __shared__ __align__(16) ushort_t As[2][4096];
  __shared__ __align__(16) ushort_t Bs[2][4096];
  int t = threadIdx.x, lane = t & 63, w = t >> 6;
  int lq = lane & 15, g = lane >> 4;
  int m0 = blockIdx.y * 128, n0 = blockIdx.x * 128;
  const ushort_t* Ab = A + (long long)blockIdx.z * sA + (long long)m0 * K;
  const ushort_t* Bb = Bm + (long long)n0 * K;

  f32x4 acc[4][4];
#pragma unroll
  for (int mi = 0; mi < 4; ++mi)
#pragma unroll
    for (int ni = 0; ni < 4; ++ni) acc[mi][ni] = (f32x4){0.f, 0.f, 0.f, 0.f};

  stage_tile(Ab, As[0], w, lane);
  stage_tile(Bb, Bs[0], w, lane);
  __syncthreads();
  int wm = w >> 1, wn = w & 1;
  for (int kt = 0; kt < K / 32; ++kt) {
    int buf = kt & 1;
    if (kt + 1 < K / 32) {
      stage_tile(Ab + (kt + 1) * 32, As[buf ^ 1], w, lane);
      stage_tile(Bb + (kt + 1) * 32, Bs[buf ^ 1], w, lane);
    }
    bf16x8 aF[4], bF[4];
#pragma unroll
    for (int mi = 0; mi < 4; ++mi)
      aF[mi] = *(const bf16x8*)&As[buf][(wm * 64 + mi * 16 + lq) * 32 + g * 8];
#pragma unroll
    for (int ni = 0; ni < 4; ++ni)
      bF[ni] = *(const bf16x8*)&Bs[buf][(wn * 64 + ni * 16 + lq) * 32 + g * 8];
#pragma unroll
    for (int mi = 0; mi < 4; ++mi)
#pragma unroll
      for (int ni = 0; ni < 4; ++ni)
        acc[mi][ni] = __builtin_amdgcn_mfma_f32_16x16x32_bf16(aF[mi], bF[ni], acc[mi][ni], 0, 0, 0);
    __syncthreads();
  }
#pragma unroll
  for (int ni = 0; ni < 4; ++ni) {
    int col = n0 + wn * 64 + ni * 16 + lq;
    float bc = bias[col];
#pragma unroll
    for (int mi = 0; mi < 4; ++mi) {
      int row0 = m0 + wm * 64 + mi * 16 + 4 * g;
      f32x4 v = acc[mi][ni];
#pragma unroll
      for (int r = 0; r < 4; ++r) v[r] += bc;
      *(f32x4*)(C + (long long)blockIdx.z * sC + (long long)col * LDo + row0) = v;
    }
  }
}

// ---------------- fused flash attention per (b, h, q-tile 128) — BARRIER-FREE ----------------
// K/V are L2-resident per head (256 KB each); fragments loaded straight from
// global. Only per-wave P staging uses LDS (XOR-swizzled, wave-local ordering).
__global__ __launch_bounds__(256) void k_attn(
    const ushort_t* __restrict__ qpT, const ushort_t* __restrict__ kpT,
    const ushort_t* __restrict__ vp, const float* __restrict__ mask,
    ushort_t* __restrict__ attnT) {
  int t = threadIdx.x, lane = t & 63, w = t >> 6;
  int lq = lane & 15, g = lane >> 4;
  int sw = lq >> 2;
  int qt = blockIdx.x, h = blockIdx.y, b = blockIdx.z;
  int q0 = qt * 128;
  long long s2 = (long long)SS * EE;
  const ushort_t* qT = qpT + b * s2;
  const ushort_t* kTb = kpT + b * s2 + h * 64;                 // [s][c] + head col
  const ushort_t* vB = vp + b * s2 + (long long)(h * 64) * SS; // [c][s] + head row
  const float* mk = mask + (long long)b * SS * SS;             // [k][q] natural
  ushort_t* aT = attnT + b * s2;

  __shared__ __align__(16) ushort_t Pt[4][2048];  // per-wave [ch2][q32][k32 swz]

  int qglob = q0 + w * 32;
  const float* mbase = mk + qglob + lq;

  // Q fragments hoisted to registers (B-operand layout)
  bf16x8 qF[2][2];
#pragma unroll
  for (int qf = 0; qf < 2; ++qf)
#pragma unroll
    for (int ch = 0; ch < 2; ++ch)
      qF[qf][ch] = *(const bf16x8*)(qT + (long long)(qglob + qf * 16 + lq) * EE +
                                    h * 64 + ch * 32 + g * 8);

  f32x4 accO[4][2];
#pragma unroll
  for (int cf = 0; cf < 4; ++cf)
#pragma unroll
    for (int qf = 0; qf < 2; ++qf) accO[cf][qf] = (f32x4){0.f, 0.f, 0.f, 0.f};
  float mrun[2] = {-3e38f, -3e38f};
  float lrun[2] = {0.f, 0.f};

  // rotated K prefetch: aKn holds fragments for the CURRENT kt at loop top
  bf16x8 aKn[2][4];
#pragma unroll
  for (int ch = 0; ch < 2; ++ch)
#pragma unroll
    for (int kf = 0; kf < 4; ++kf)
      aKn[ch][kf] = *(const bf16x8*)(kTb + (long long)(kf * 16 + lq) * EE + ch * 32 + g * 8);

#pragma unroll 1
  for (int kt = 0; kt < SS / 64; ++kt) {
    int k0 = kt * 64;
    bf16x8 aK[2][4];
#pragma unroll
    for (int ch = 0; ch < 2; ++ch)
#pragma unroll
      for (int kf = 0; kf < 4; ++kf) aK[ch][kf] = aKn[ch][kf];
    if (kt + 1 < SS / 64) {
#pragma unroll
      for (int ch = 0; ch < 2; ++ch)
#pragma unroll
        for (int kf = 0; kf < 4; ++kf)
          aKn[ch][kf] = *(const bf16x8*)(kTb + (long long)(k0 + 64 + kf * 16 + lq) * EE + ch * 32 + g * 8);
    }
    // V fragments (A-operand of PV), consumed at the end of the body
    bf16x8 vF[4][2];
#pragma unroll
    for (int cf = 0; cf < 4; ++cf)
#pragma unroll
      for (int ch = 0; ch < 2; ++ch)
        vF[cf][ch] = *(const bf16x8*)(vB + (long long)(cf * 16 + lq) * SS + k0 + ch * 32 + 8 * g);
    // mask, natural [k][q] layout == accS C/D fragment layout
    float mv[4][2][4];
#pragma unroll
    for (int kf = 0; kf < 4; ++kf)
#pragma unroll
      for (int r = 0; r < 4; ++r) {
        const float* mrow = mbase + (long long)(k0 + kf * 16 + 4 * g + r) * SS;
        mv[kf][0][r] = mrow[0];
        mv[kf][1][r] = mrow[16];
      }

    // QK^T (swapped: A=K rows, B=Q) -> accS[k][q], log2 domain
    f32x4 accS[4][2];
#pragma unroll
    for (int kf = 0; kf < 4; ++kf)
#pragma unroll
      for (int qf = 0; qf < 2; ++qf) accS[kf][qf] = (f32x4){0.f, 0.f, 0.f, 0.f};
    __builtin_amdgcn_s_setprio(1);
#pragma unroll
    for (int ch = 0; ch < 2; ++ch)
#pragma unroll
      for (int kf = 0; kf < 4; ++kf)
#pragma unroll
        for (int qf = 0; qf < 2; ++qf)
          accS[kf][qf] = __builtin_amdgcn_mfma_f32_16x16x32_bf16(aK[ch][kf], qF[qf][ch], accS[kf][qf], 0, 0, 0);
    __builtin_amdgcn_s_setprio(0);

    // online softmax per qf (defer-max THR=8 in log2 domain)
#pragma unroll
    for (int qf = 0; qf < 2; ++qf) {
      float sv[4][4];
      float tm = -3e38f;
#pragma unroll
      for (int kf = 0; kf < 4; ++kf)
#pragma unroll
        for (int r = 0; r < 4; ++r) {
          sv[kf][r] = fmaf(mv[kf][qf][r], L2E, accS[kf][qf][r]);
          tm = fmaxf(tm, sv[kf][r]);
        }
      tm = fmaxf(tm, __shfl_xor(tm, 16));
      tm = fmaxf(tm, __shfl_xor(tm, 32));
      if (__any(tm > mrun[qf] + 8.0f)) {
        float mnew = fmaxf(mrun[qf], tm);
        float corr = __builtin_amdgcn_exp2f(mrun[qf] - mnew);
        lrun[qf] *= corr;
#pragma unroll
        for (int cf = 0; cf < 4; ++cf) accO[cf][qf] = accO[cf][qf] * corr;
        mrun[qf] = mnew;
      }
      float m = mrun[qf];
      float ps = 0.f;
      unsigned pk0[4], pk1[4];
#pragma unroll
      for (int kf = 0; kf < 4; ++kf) {
        float p0 = __builtin_amdgcn_exp2f(sv[kf][0] - m);
        float p1 = __builtin_amdgcn_exp2f(sv[kf][1] - m);
        float p2 = __builtin_amdgcn_exp2f(sv[kf][2] - m);
        float p3 = __builtin_amdgcn_exp2f(sv[kf][3] - m);
        ps += (p0 + p1) + (p2 + p3);
        pk0[kf] = cvtpk(p0, p1);
        pk1[kf] = cvtpk(p2, p3);
      }
      ps += __shfl_xor(ps, 16);
      ps += __shfl_xor(ps, 32);
      lrun[qf] += ps;
      int row = qf * 16 + lq;
#pragma unroll
      for (int kf = 0; kf < 4; ++kf) {
        int slot = ((kf & 1) * 2 + (g >> 1)) ^ sw;
        u32x2 pkv = {pk0[kf], pk1[kf]};
        *(u32x2*)&Pt[w][(kf >> 1) * 1024 + row * 32 + slot * 8 + (g & 1) * 4] = pkv;
      }
    }

    // PV: accO[c][q] += V[c][k] * P[k][q]
    __builtin_amdgcn_s_setprio(1);
#pragma unroll
    for (int ch = 0; ch < 2; ++ch) {
      bf16x8 bP[2];
#pragma unroll
      for (int qf = 0; qf < 2; ++qf)
        bP[qf] = *(const bf16x8*)&Pt[w][ch * 1024 + (qf * 16 + lq) * 32 + (g ^ sw) * 8];
#pragma unroll
      for (int cf = 0; cf < 4; ++cf)
#pragma unroll
        for (int qf = 0; qf < 2; ++qf)
          accO[cf][qf] = __builtin_amdgcn_mfma_f32_16x16x32_bf16(vF[cf][ch], bP[qf], accO[cf][qf], 0, 0, 0);
    }
    __builtin_amdgcn_s_setprio(0);
  }

  // epilogue: normalize, write attnT[s][c] bf16
#pragma unroll
  for (int qf = 0; qf < 2; ++qf) {
    float inv = 1.f / lrun[qf];
    int s = qglob + qf * 16 + lq;
#pragma unroll
    for (int cf = 0; cf < 4; ++cf) {
      int c0 = h * 64 + cf * 16 + 4 * g;
      f32x4 v = accO[cf][qf];
      u32x2 pk = {cvtpk(v[0] * inv, v[1] * inv), cvtpk(v[2] * inv, v[3] * inv)};
      *(u32x2*)(aT + (long long)s * EE + c0) = pk;
    }
  }
}

extern "C" void kernel_launch(void* const* d_in, const int* in_sizes, int n_in,
                              void* d_out, int out_size, void* d_ws, size_t ws_size,
                              hipStream_t stream) {
  const float* q = (const float*)d_in[0];
  const float* k = (const float*)d_in[1];
  const float* v = (const float*)d_in[2];
  const float* mask = (const float*)d_in[3];
  const float* Wq = (const float*)d_in[4];
  const float* bq = (const float*)d_in[5];
  const float* Wk = (const float*)d_in[6];
  const float* bk = (const float*)d_in[7];
  const float* Wv = (const float*)d_in[8];
  const float* bv = (const float*)d_in[9];
  const float* Wo = (const float*)d_in[10];
  const float* bo = (const float*)d_in[11];
  float* out = (float*)d_out;

  char* ws = (char*)d_ws;
  const long long MB = 1024LL * 1024LL;
  ushort_t* xqT = (ushort_t*)(ws + 0 * MB);   // [b][s][e] bf16, 8MB
  ushort_t* xkT = (ushort_t*)(ws + 8 * MB);
  ushort_t* xvT = (ushort_t*)(ws + 16 * MB);
  ushort_t* wqB = (ushort_t*)(ws + 24 * MB);  // 2MB each
  ushort_t* wkB = (ushort_t*)(ws + 26 * MB);
  ushort_t* wvB = (ushort_t*)(ws + 28 * MB);
  ushort_t* woB = (ushort_t*)(ws + 30 * MB);
  ushort_t* qpT = (ushort_t*)(ws + 32 * MB);  // [b][s][c] scaled, 8MB
  ushort_t* kpT = (ushort_t*)(ws + 40 * MB);  // [b][s][c]
  ushort_t* vpN = (ushort_t*)(ws + 48 * MB);  // [b][c][s]
  ushort_t* anT = (ushort_t*)(ws + 56 * MB);  // [b][s][c]

  TpArgs tp{q, k, v, xqT, xkT, xvT};
  hipLaunchKernelGGL(k_transpose_cvt, dim3(SS / 64, EE / 64, 6), dim3(256), 0, stream, tp);
  WArgs wa{Wq, Wk, Wv, Wo, wqB, wkB, wvB, woB};
  hipLaunchKernelGGL(k_cvt_w, dim3(1024, 4, 1), dim3(256), 0, stream, wa);

  // merged q/k/v projections: grid z = pair*2 + b
  hipLaunchKernelGGL(k_proj, dim3(SS / 128, EE / 128, 6), dim3(256), 0, stream,
                     xqT, xkT, xvT, wqB, wkB, wvB, bq, bk, bv, qpT, kpT, vpN);
  // attention (barrier-free)
  hipLaunchKernelGGL(k_attn, dim3(SS / 128, HH, BB), dim3(256), 0, stream,
                     qpT, kpT, vpN, mask, anT);
  // out: D[m=s][n=o] -> out[o][s] f32, bias on cols (o)
  long long s2 = (long long)SS * EE;
  hipLaunchKernelGGL(k_gemm_out, dim3(EE / 128, SS / 128, BB), dim3(256), 0, stream,
                     anT, s2, woB, out, s2, bo, SS);
}

// Round 4
// 163.852 us; speedup vs baseline: 1.6806x; 1.3852x over previous
//
#include <hip/hip_runtime.h>
#include <hip/hip_bf16.h>

typedef unsigned short ushort_t;
typedef __attribute__((ext_vector_type(8))) __bf16 bf16x8;
typedef __attribute__((ext_vector_type(4))) float f32x4;
typedef __attribute__((ext_vector_type(2))) unsigned int u32x2;
typedef __attribute__((ext_vector_type(8))) unsigned short us8;

#define DEV __device__ __forceinline__

constexpr int BB = 2, EE = 1024, SS = 2048, HH = 16;
constexpr float L2E = 1.44269504088896f;
constexpr float SCALE_Q = 0.125f * 1.44269504088896f; // dh^-0.5 * log2(e) folded

DEV ushort_t f2bf(float x) {
  union { float f; unsigned u; } c; c.f = x;
  unsigned u = c.u;
  return (ushort_t)((u + 0x7fffu + ((u >> 16) & 1u)) >> 16); // RNE
}

DEV unsigned cvtpk(float lo, float hi) {
  unsigned r;
  asm volatile("v_cvt_pk_bf16_f32 %0, %1, %2" : "=v"(r) : "v"(lo), "v"(hi));
  return r;
}

DEV void gload16(const void* g, void* l) {
  __builtin_amdgcn_global_load_lds((const __attribute__((address_space(1))) void*)g,
                                   (__attribute__((address_space(3))) void*)l, 16, 0, 0);
}

// ---------------- prep: transpose + f32->bf16 (q,k,v -> [b][s][e]) ----------------
struct TpArgs { const float* i0; const float* i1; const float* i2;
                ushort_t* o0; ushort_t* o1; ushort_t* o2; };

__global__ __launch_bounds__(256) void k_transpose_cvt(TpArgs a) {
  int z = blockIdx.z; int p = z >> 1; int b = z & 1;
  const float* in = (p == 0) ? a.i0 : (p == 1) ? a.i1 : a.i2;
  ushort_t* out = (p == 0) ? a.o0 : (p == 1) ? a.o1 : a.o2;
  in += (long long)b * EE * SS;
  out += (long long)b * SS * EE;
  int s0 = blockIdx.x * 64, e0 = blockIdx.y * 64;
  __shared__ __align__(16) ushort_t T[64][72];
  int t = threadIdx.x;
  int sc = (t & 15) * 4, erb = t >> 4;
#pragma unroll
  for (int it = 0; it < 4; ++it) {
    int er = erb + it * 16;
    float4 v = *(const float4*)(in + (long long)(e0 + er) * SS + s0 + sc);
    T[sc + 0][er] = f2bf(v.x);
    T[sc + 1][er] = f2bf(v.y);
    T[sc + 2][er] = f2bf(v.z);
    T[sc + 3][er] = f2bf(v.w);
  }
  __syncthreads();
#pragma unroll
  for (int it = 0; it < 2; ++it) {
    int slot = t + it * 256;
    int sr = slot >> 3, ec = (slot & 7) * 8;
    us8 v = *(const us8*)&T[sr][ec];
    *(us8*)(out + (long long)(s0 + sr) * EE + e0 + ec) = v;
  }
}

// ---------------- prep: W f32 -> bf16 ----------------
struct WArgs { const float* w0; const float* w1; const float* w2; const float* w3;
               ushort_t* o0; ushort_t* o1; ushort_t* o2; ushort_t* o3; };

__global__ __launch_bounds__(256) void k_cvt_w(WArgs a) {
  int y = blockIdx.y;
  const float* in = (y == 0) ? a.w0 : (y == 1) ? a.w1 : (y == 2) ? a.w2 : a.w3;
  ushort_t* out = (y == 0) ? a.o0 : (y == 1) ? a.o1 : (y == 2) ? a.o2 : a.o3;
  long long idx = ((long long)blockIdx.x * 256 + threadIdx.x) * 4;
  float4 v = *(const float4*)(in + idx);
  unsigned lo = f2bf(v.x) | ((unsigned)f2bf(v.y) << 16);
  unsigned hi = f2bf(v.z) | ((unsigned)f2bf(v.w) << 16);
  u32x2 pk = {lo, hi};
  *(u32x2*)(out + idx) = pk;
}

// ---------------- GEMM core helpers ----------------
DEV void stage_tile(const ushort_t* src0, ushort_t* dst0, int w, int lane) {
#pragma unroll
  for (int i = 0; i < 2; ++i) {
    int u = w * 128 + i * 64 + lane;
    int row = u >> 2, part = u & 3;
    gload16(src0 + (long long)row * 1024 + part * 8, dst0 + (w * 128 + i * 64) * 8);
  }
}

// ---------------- merged projection GEMMs: z = pair*2+b, pair in {q,k,v} ----------------
__global__ __launch_bounds__(256) void k_proj(
    const ushort_t* __restrict__ xq, const ushort_t* __restrict__ xk,
    const ushort_t* __restrict__ xv, const ushort_t* __restrict__ wq,
    const ushort_t* __restrict__ wk, const ushort_t* __restrict__ wv,
    const float* __restrict__ bqp, const float* __restrict__ bkp,
    const float* __restrict__ bvp,
    ushort_t* __restrict__ qpT, ushort_t* __restrict__ kpT,
    ushort_t* __restrict__ vpN) {
  constexpr int K = 1024;
  __shared__ __align__(16) ushort_t As[2][4096];
  __shared__ __align__(16) ushort_t Bs[2][4096];
  int t = threadIdx.x, lane = t & 63, w = t >> 6;
  int lq = lane & 15, g = lane >> 4;
  int z = blockIdx.z, pair = z >> 1, b = z & 1;
  long long s2 = (long long)SS * EE;
  int m0, n0, LDo; bool browq; float scale; const float* bias;
  const ushort_t *Ab, *Bb; ushort_t* Co;
  if (pair < 2) {
    m0 = blockIdx.y * 128; n0 = blockIdx.x * 128;
    Ab = (pair == 0 ? wq : wk) + (long long)m0 * K;
    Bb = (pair == 0 ? xq : xk) + b * s2 + (long long)n0 * K;
    Co = (pair == 0 ? qpT : kpT) + b * s2;
    bias = (pair == 0 ? bqp : bkp);
    scale = (pair == 0 ? SCALE_Q : 1.0f);
    LDo = EE; browq = true;
  } else {
    m0 = blockIdx.x * 128; n0 = blockIdx.y * 128;
    Ab = xv + b * s2 + (long long)m0 * K;
    Bb = wv + (long long)n0 * K;
    Co = vpN + b * s2;
    bias = bvp; scale = 1.0f; LDo = SS; browq = false;
  }

  f32x4 acc[4][4];
#pragma unroll
  for (int mi = 0; mi < 4; ++mi)
#pragma unroll
    for (int ni = 0; ni < 4; ++ni) acc[mi][ni] = (f32x4){0.f, 0.f, 0.f, 0.f};

  stage_tile(Ab, As[0], w, lane);
  stage_tile(Bb, Bs[0], w, lane);
  __syncthreads();
  int wm = w >> 1, wn = w & 1;
  for (int kt = 0; kt < K / 32; ++kt) {
    int buf = kt & 1;
    if (kt + 1 < K / 32) {
      stage_tile(Ab + (kt + 1) * 32, As[buf ^ 1], w, lane);
      stage_tile(Bb + (kt + 1) * 32, Bs[buf ^ 1], w, lane);
    }
    bf16x8 aF[4], bF[4];
#pragma unroll
    for (int mi = 0; mi < 4; ++mi)
      aF[mi] = *(const bf16x8*)&As[buf][(wm * 64 + mi * 16 + lq) * 32 + g * 8];
#pragma unroll
    for (int ni = 0; ni < 4; ++ni)
      bF[ni] = *(const bf16x8*)&Bs[buf][(wn * 64 + ni * 16 + lq) * 32 + g * 8];
#pragma unroll
    for (int mi = 0; mi < 4; ++mi)
#pragma unroll
      for (int ni = 0; ni < 4; ++ni)
        acc[mi][ni] = __builtin_amdgcn_mfma_f32_16x16x32_bf16(aF[mi], bF[ni], acc[mi][ni], 0, 0, 0);
    __syncthreads();
  }
#pragma unroll
  for (int ni = 0; ni < 4; ++ni) {
    int col = n0 + wn * 64 + ni * 16 + lq;
    float bc = browq ? 0.f : bias[col];
#pragma unroll
    for (int mi = 0; mi < 4; ++mi) {
      int row0 = m0 + wm * 64 + mi * 16 + 4 * g;
      f32x4 v = acc[mi][ni];
#pragma unroll
      for (int r = 0; r < 4; ++r) {
        float bb = browq ? bias[row0 + r] : bc;
        v[r] = (v[r] + bb) * scale;
      }
      u32x2 pk = {cvtpk(v[0], v[1]), cvtpk(v[2], v[3])};
      *(u32x2*)(Co + (long long)col * LDo + row0) = pk;
    }
  }
}

// ---------------- final GEMM: out f32 [col][row] ----------------
__global__ __launch_bounds__(256) void k_gemm_out(
    const ushort_t* __restrict__ A, long long sA,
    const ushort_t* __restrict__ Bm,
    float* __restrict__ C, long long sC,
    const float* __restrict__ bias, int LDo) {
  constexpr int K = 1024;
  __shared__ __align__(16) ushort_t As[2][4096];
  __shared__ __align__(16) ushort_t Bs[2][4096];
  int t = threadIdx.x, lane = t & 63, w = t >> 6;
  int lq = lane & 15, g = lane >> 4;
  int m0 = blockIdx.y * 128, n0 = blockIdx.x * 128;
  const ushort_t* Ab = A + (long long)blockIdx.z * sA + (long long)m0 * K;
  const ushort_t* Bb = Bm + (long long)n0 * K;

  f32x4 acc[4][4];
#pragma unroll
  for (int mi = 0; mi < 4; ++mi)
#pragma unroll
    for (int ni = 0; ni < 4; ++ni) acc[mi][ni] = (f32x4){0.f, 0.f, 0.f, 0.f};

  stage_tile(Ab, As[0], w, lane);
  stage_tile(Bb, Bs[0], w, lane);
  __syncthreads();
  int wm = w >> 1, wn = w & 1;
  for (int kt = 0; kt < K / 32; ++kt) {
    int buf = kt & 1;
    if (kt + 1 < K / 32) {
      stage_tile(Ab + (kt + 1) * 32, As[buf ^ 1], w, lane);
      stage_tile(Bb + (kt + 1) * 32, Bs[buf ^ 1], w, lane);
    }
    bf16x8 aF[4], bF[4];
#pragma unroll
    for (int mi = 0; mi < 4; ++mi)
      aF[mi] = *(const bf16x8*)&As[buf][(wm * 64 + mi * 16 + lq) * 32 + g * 8];
#pragma unroll
    for (int ni = 0; ni < 4; ++ni)
      bF[ni] = *(const bf16x8*)&Bs[buf][(wn * 64 + ni * 16 + lq) * 32 + g * 8];
#pragma unroll
    for (int mi = 0; mi < 4; ++mi)
#pragma unroll
      for (int ni = 0; ni < 4; ++ni)
        acc[mi][ni] = __builtin_amdgcn_mfma_f32_16x16x32_bf16(aF[mi], bF[ni], acc[mi][ni], 0, 0, 0);
    __syncthreads();
  }
#pragma unroll
  for (int ni = 0; ni < 4; ++ni) {
    int col = n0 + wn * 64 + ni * 16 + lq;
    float bc = bias[col];
#pragma unroll
    for (int mi = 0; mi < 4; ++mi) {
      int row0 = m0 + wm * 64 + mi * 16 + 4 * g;
      f32x4 v = acc[mi][ni];
#pragma unroll
      for (int r = 0; r < 4; ++r) v[r] += bc;
      *(f32x4*)(C + (long long)blockIdx.z * sC + (long long)col * LDo + row0) = v;
    }
  }
}

// ---------------- fused flash attention ----------------
// Block = 4 waves, q-tile 64 (16 q-rows per wave) -> 4096 waves total =
// 16 waves/CU (4/SIMD, from 4 different blocks per SIMD). K and V staged
// block-shared in LDS (dbuf, 40KB total -> 4 blocks/CU), XOR-swizzled via
// pre-swizzled global source (rule #21). Mask loaded per-lane f32 (natural
// [k][q] layout == accS fragment layout), issued at top of body.
__global__ __launch_bounds__(256, 4) void k_attn(
    const ushort_t* __restrict__ qpT, const ushort_t* __restrict__ kpT,
    const ushort_t* __restrict__ vp, const float* __restrict__ mask,
    ushort_t* __restrict__ attnT) {
  int t = threadIdx.x, lane = t & 63, w = t >> 6;
  int lq = lane & 15, g = lane >> 4;
  int sw = lq >> 2;          // P-tile swizzle (4 slots/row)
  int kvsw = lq & 7;         // K/V-tile swizzle (8 slots/row)
  int qt = blockIdx.x, h = blockIdx.y, b = blockIdx.z;
  int q0 = qt * 64;
  long long s2 = (long long)SS * EE;
  const ushort_t* qT = qpT + b * s2;
  const ushort_t* kTb = kpT + b * s2 + h * 64;                 // [s][c] head col
  const ushort_t* vB = vp + b * s2 + (long long)(h * 64) * SS; // [c][s] head row
  const float* mk = mask + (long long)b * SS * SS;             // [k][q] natural
  ushort_t* aT = attnT + b * s2;

  __shared__ __align__(16) ushort_t Kt[2][4096]; // [k64][slot8^(k&7)][8]
  __shared__ __align__(16) ushort_t Vt[2][4096]; // [c64][slot8^(c&7)][8]
  __shared__ __align__(16) ushort_t Pt[4][1024]; // per-wave [ch2][q16][k32 swz]

  int qglob = q0 + w * 16;
  const float* mbase = mk + qglob + lq;

  // Q fragments (B-operand): row=q=lq, elems ch*32+g*8
  bf16x8 qF[2];
#pragma unroll
  for (int ch = 0; ch < 2; ++ch)
    qF[ch] = *(const bf16x8*)(qT + (long long)(qglob + lq) * EE + h * 64 + ch * 32 + g * 8);

  // stage lambda: wave w covers rows w*16..w*16+15 of the 64-row tile
  int srow = (lane >> 3);          // row-within-8 for this lane
  int sslot = lane & 7;            // linear LDS slot
  auto stageKV = [&](int buf, int k0) {
#pragma unroll
    for (int i = 0; i < 2; ++i) {
      int row = w * 16 + i * 8 + srow;
      int ps = sslot ^ (row & 7);  // inverse swizzle on global source
      gload16(kTb + (long long)(k0 + row) * EE + ps * 8,
              &Kt[buf][(w * 16 + i * 8) * 64]);
      gload16(vB + (long long)row * SS + k0 + ps * 8,
              &Vt[buf][(w * 16 + i * 8) * 64]);
    }
  };

  stageKV(0, 0);
  __syncthreads();

  f32x4 accO[4];
#pragma unroll
  for (int cf = 0; cf < 4; ++cf) accO[cf] = (f32x4){0.f, 0.f, 0.f, 0.f};
  float mrun = -3e38f, lrun = 0.f;

#pragma unroll 1
  for (int kt = 0; kt < SS / 64; ++kt) {
    int k0 = kt * 64;
    int cur = kt & 1;
    if (kt + 1 < SS / 64) stageKV(cur ^ 1, k0 + 64);

    // mask loads (consumed by softmax mid-body)
    float mv[4][4];
#pragma unroll
    for (int kf = 0; kf < 4; ++kf)
#pragma unroll
      for (int r = 0; r < 4; ++r)
        mv[kf][r] = mbase[(long long)(k0 + kf * 16 + 4 * g + r) * SS];

    // QK^T (A=K rows from LDS, B=Q regs) -> accS[kf], log2 domain
    f32x4 accS[4];
#pragma unroll
    for (int kf = 0; kf < 4; ++kf) accS[kf] = (f32x4){0.f, 0.f, 0.f, 0.f};
    __builtin_amdgcn_s_setprio(1);
#pragma unroll
    for (int ch = 0; ch < 2; ++ch) {
      bf16x8 aK[4];
#pragma unroll
      for (int kf = 0; kf < 4; ++kf) {
        int row = kf * 16 + lq;
        aK[kf] = *(const bf16x8*)&Kt[cur][row * 64 + (((ch * 4 + g) ^ kvsw) * 8)];
      }
#pragma unroll
      for (int kf = 0; kf < 4; ++kf)
        accS[kf] = __builtin_amdgcn_mfma_f32_16x16x32_bf16(aK[kf], qF[ch], accS[kf], 0, 0, 0);
    }
    __builtin_amdgcn_s_setprio(0);

    // online softmax (defer-max THR=8, log2 domain)
    float sv[4][4];
    float tm = -3e38f;
#pragma unroll
    for (int kf = 0; kf < 4; ++kf)
#pragma unroll
      for (int r = 0; r < 4; ++r) {
        sv[kf][r] = fmaf(mv[kf][r], L2E, accS[kf][r]);
        tm = fmaxf(tm, sv[kf][r]);
      }
    tm = fmaxf(tm, __shfl_xor(tm, 16));
    tm = fmaxf(tm, __shfl_xor(tm, 32));
    if (__any(tm > mrun + 8.0f)) {
      float mnew = fmaxf(mrun, tm);
      float corr = __builtin_amdgcn_exp2f(mrun - mnew);
      lrun *= corr;
#pragma unroll
      for (int cf = 0; cf < 4; ++cf) accO[cf] = accO[cf] * corr;
      mrun = mnew;
    }
    float ps = 0.f;
    unsigned pk0[4], pk1[4];
#pragma unroll
    for (int kf = 0; kf < 4; ++kf) {
      float p0 = __builtin_amdgcn_exp2f(sv[kf][0] - mrun);
      float p1 = __builtin_amdgcn_exp2f(sv[kf][1] - mrun);
      float p2 = __builtin_amdgcn_exp2f(sv[kf][2] - mrun);
      float p3 = __builtin_amdgcn_exp2f(sv[kf][3] - mrun);
      ps += (p0 + p1) + (p2 + p3);
      pk0[kf] = cvtpk(p0, p1);
      pk1[kf] = cvtpk(p2, p3);
    }
    ps += __shfl_xor(ps, 16);
    ps += __shfl_xor(ps, 32);
    lrun += ps;
#pragma unroll
    for (int kf = 0; kf < 4; ++kf) {
      int slot = ((kf & 1) * 2 + (g >> 1)) ^ sw;
      u32x2 pkv = {pk0[kf], pk1[kf]};
      *(u32x2*)&Pt[w][(kf >> 1) * 512 + lq * 32 + slot * 8 + (g & 1) * 4] = pkv;
    }

    // PV: accO[cf] += V[c][k] * P[k][q]
    __builtin_amdgcn_s_setprio(1);
#pragma unroll
    for (int ch = 0; ch < 2; ++ch) {
      bf16x8 bP = *(const bf16x8*)&Pt[w][ch * 512 + lq * 32 + (g ^ sw) * 8];
#pragma unroll
      for (int cf = 0; cf < 4; ++cf) {
        int row = cf * 16 + lq;
        bf16x8 vF = *(const bf16x8*)&Vt[cur][row * 64 + (((ch * 4 + g) ^ kvsw) * 8)];
        accO[cf] = __builtin_amdgcn_mfma_f32_16x16x32_bf16(vF, bP, accO[cf], 0, 0, 0);
      }
    }
    __builtin_amdgcn_s_setprio(0);
    __syncthreads();
  }

  // epilogue: normalize, write attnT[s][c] bf16
  float inv = 1.f / lrun;
  int s = qglob + lq;
#pragma unroll
  for (int cf = 0; cf < 4; ++cf) {
    int c0 = h * 64 + cf * 16 + 4 * g;
    f32x4 v = accO[cf];
    u32x2 pk = {cvtpk(v[0] * inv, v[1] * inv), cvtpk(v[2] * inv, v[3] * inv)};
    *(u32x2*)(aT + (long long)s * EE + c0) = pk;
  }
}

extern "C" void kernel_launch(void* const* d_in, const int* in_sizes, int n_in,
                              void* d_out, int out_size, void* d_ws, size_t ws_size,
                              hipStream_t stream) {
  const float* q = (const float*)d_in[0];
  const float* k = (const float*)d_in[1];
  const float* v = (const float*)d_in[2];
  const float* mask = (const float*)d_in[3];
  const float* Wq = (const float*)d_in[4];
  const float* bq = (const float*)d_in[5];
  const float* Wk = (const float*)d_in[6];
  const float* bk = (const float*)d_in[7];
  const float* Wv = (const float*)d_in[8];
  const float* bv = (const float*)d_in[9];
  const float* Wo = (const float*)d_in[10];
  const float* bo = (const float*)d_in[11];
  float* out = (float*)d_out;

  char* ws = (char*)d_ws;
  const long long MB = 1024LL * 1024LL;
  ushort_t* xqT = (ushort_t*)(ws + 0 * MB);   // [b][s][e] bf16, 8MB
  ushort_t* xkT = (ushort_t*)(ws + 8 * MB);
  ushort_t* xvT = (ushort_t*)(ws + 16 * MB);
  ushort_t* wqB = (ushort_t*)(ws + 24 * MB);  // 2MB each
  ushort_t* wkB = (ushort_t*)(ws + 26 * MB);
  ushort_t* wvB = (ushort_t*)(ws + 28 * MB);
  ushort_t* woB = (ushort_t*)(ws + 30 * MB);
  ushort_t* qpT = (ushort_t*)(ws + 32 * MB);  // [b][s][c] scaled, 8MB
  ushort_t* kpT = (ushort_t*)(ws + 40 * MB);  // [b][s][c]
  ushort_t* vpN = (ushort_t*)(ws + 48 * MB);  // [b][c][s]
  ushort_t* anT = (ushort_t*)(ws + 56 * MB);  // [b][s][c]

  TpArgs tp{q, k, v, xqT, xkT, xvT};
  hipLaunchKernelGGL(k_transpose_cvt, dim3(SS / 64, EE / 64, 6), dim3(256), 0, stream, tp);
  WArgs wa{Wq, Wk, Wv, Wo, wqB, wkB, wvB, woB};
  hipLaunchKernelGGL(k_cvt_w, dim3(1024, 4, 1), dim3(256), 0, stream, wa);

  // merged q/k/v projections: grid z = pair*2 + b
  hipLaunchKernelGGL(k_proj, dim3(SS / 128, EE / 128, 6), dim3(256), 0, stream,
                     xqT, xkT, xvT, wqB, wkB, wvB, bq, bk, bv, qpT, kpT, vpN);
  // attention: block = 4 waves x 16 q-rows -> q-tile 64
  hipLaunchKernelGGL(k_attn, dim3(SS / 64, HH, BB), dim3(256), 0, stream,
                     qpT, kpT, vpN, mask, anT);
  // out: D[m=s][n=o] -> out[o][s] f32, bias on cols (o)
  long long s2 = (long long)SS * EE;
  hipLaunchKernelGGL(k_gemm_out, dim3(EE / 128, SS / 128, BB), dim3(256), 0, stream,
                     anT, s2, woB, out, s2, bo, SS);
}